// Round 15
// baseline (275.919 us; speedup 1.0000x reference)
//
#include <hip/hip_runtime.h>
#include <math.h>

#define N_NODES 50000
#define M_PAD   50048            /* 391*128 = 782*64 */
#define N_EDGES 800000
#define EP (N_EDGES + N_NODES)
#define DIN 256
#define HEADS 4
#define HID 64
#define F1 256
#define F2 128
#define NEG_SLOPE 0.2f
#define SCAN_NBLK ((N_NODES + 255)/256)   /* 196 */
#define HIST_NB ((EP + 255)/256)          /* 3321 */
#define SA_NB (M_PAD*F1/4/256)            /* 12512 */
#define WT_TOT (DIN*F1 + F1*F2)
#define WT_NB ((WT_TOT + 255)/256)        /* 384 */
#define GEMM1_NB (M_PAD/64)               /* 782 */

typedef short bf16x8 __attribute__((ext_vector_type(8)));
typedef float f32x4  __attribute__((ext_vector_type(4)));

static __device__ __forceinline__ float leaky(float x){ return x > 0.f ? x : NEG_SLOPE*x; }
static __device__ __forceinline__ float elu_f(float x){ return x > 0.f ? x : (__expf(x)-1.f); }
static __device__ __forceinline__ float b2f(unsigned short u){ return __uint_as_float(((unsigned)u)<<16); }
static __device__ __forceinline__ unsigned short f2b(float f){
  unsigned u = __float_as_uint(f);
  return (unsigned short)((u + 0x7fffu + ((u>>16)&1u)) >> 16);   // RNE
}

// ---------------- fused prep: splitA | splitWT(W1,W2) | edge histogram (+rank) ----------------
__global__ __launch_bounds__(256) void k_prep(const float* __restrict__ X, unsigned short* __restrict__ Ahi,
    const float* __restrict__ W1, const float* __restrict__ W2,
    unsigned short* __restrict__ Bt1, unsigned short* __restrict__ Bt2,
    const int* __restrict__ dst, int* __restrict__ counts, int* __restrict__ rank){
  unsigned b = blockIdx.x;
  if (b < SA_NB){
    int gid = b*256 + threadIdx.x;
    size_t base = (size_t)gid*4;
    int row = (int)(base >> 8);
    ushort4 hi;
    if (row < N_NODES){
      float4 v = *(const float4*)(X + base);
      hi.x=f2b(v.x); hi.y=f2b(v.y); hi.z=f2b(v.z); hi.w=f2b(v.w);
    } else {
      hi = {0,0,0,0};
    }
    *(ushort4*)(Ahi + base) = hi;
  } else if (b < SA_NB + WT_NB){
    int t = (b - SA_NB)*256 + threadIdx.x;
    if (t < DIN*F1){
      int n = t / DIN, k = t % DIN;
      Bt1[(unsigned)n*DIN + k] = f2b(W1[(unsigned)k*F1 + n]);
    } else if (t < WT_TOT){
      int u = t - DIN*F1;
      int n = u / F1, k = u % F1;
      Bt2[(unsigned)n*F1 + k] = f2b(W2[(unsigned)k*F2 + n]);
    }
  } else {
    int e = (b - SA_NB - WT_NB)*256 + threadIdx.x;
    if (e < EP){
      int d = (e < N_EDGES) ? dst[e] : (e - N_EDGES);
      rank[e] = atomicAdd(&counts[d], 1);
    }
  }
}

// ---------------- scan level 1 (+ zero dbin in block 0) ----------------
__global__ __launch_bounds__(256) void k_scan1(const int* __restrict__ counts,
                                               int* __restrict__ exc, int* __restrict__ bsum,
                                               int* __restrict__ dbin){
  if (blockIdx.x == 0) dbin[threadIdx.x] = 0;
  int i = blockIdx.x*256 + threadIdx.x;
  int v = (i < N_NODES) ? counts[i] : 0;
  int lane = threadIdx.x & 63, wave = threadIdx.x >> 6;
  int inc = v;
  #pragma unroll
  for (int off=1; off<64; off<<=1){
    int n = __shfl_up(inc, off);
    if (lane >= off) inc += n;
  }
  __shared__ int wsum[4];
  if (lane == 63) wsum[wave] = inc;
  __syncthreads();
  int wpre = 0;
  #pragma unroll
  for (int w=0; w<4; w++) if (w < wave) wpre += wsum[w];
  if (i < N_NODES) exc[i] = wpre + inc - v;
  if (threadIdx.x == 255) bsum[blockIdx.x] = wpre + inc;
}

// ---------------- scan3d: inline block-prefix + offsets + degree histogram ----------------
__global__ __launch_bounds__(256) void k_scan3d(const int* __restrict__ exc, const int* __restrict__ bsum,
                                                const int* __restrict__ counts,
                                                int* __restrict__ offsets,
                                                int* __restrict__ dbin, int* __restrict__ bcount){
  int t = threadIdx.x;
  int lane = t & 63, wave = t >> 6;
  int v = (t < (int)blockIdx.x) ? bsum[t] : 0;
  #pragma unroll
  for (int off=1; off<64; off<<=1) v += __shfl_xor(v, off);
  __shared__ int ws[4];
  __shared__ int hh[256];
  if (lane == 0) ws[wave] = v;
  hh[t] = 0;
  __syncthreads();
  int bpref = ws[0] + ws[1] + ws[2] + ws[3];
  int i = blockIdx.x*256 + t;
  if (i < N_NODES){
    int o = exc[i] + bpref;
    offsets[i] = o;
    int b = counts[i]; if (b > 255) b = 255;
    atomicAdd(&hh[b], 1);
  }
  if (i == 0) offsets[N_NODES] = EP;
  __syncthreads();
  int c = hh[t];
  bcount[(unsigned)blockIdx.x*256 + t] = c;
  if (c) atomicAdd(&dbin[t], c);
}

// ---------------- scatter (atomic-free, via rank) | dcol | node-major sdst fill ----------------
__global__ __launch_bounds__(256) void k_scatter_dcol_fill(
    const int* __restrict__ src, const int* __restrict__ dst, const int* __restrict__ rank,
    int* __restrict__ sorted_src, int* __restrict__ sorted_dst,
    const int* __restrict__ dbin, const int* __restrict__ bcount, int* __restrict__ colbase,
    const int* __restrict__ offsets){
  if (blockIdx.x < HIST_NB){
    int e = blockIdx.x*256 + threadIdx.x;
    if (e >= EP) return;
    int s, d;
    if (e < N_EDGES){ s = src[e]; d = dst[e]; } else { s = d = e - N_EDGES; }
    int pos = offsets[d] + rank[e];
    sorted_src[pos] = s;
    return;
  }
  if (blockIdx.x == HIST_NB){
    int i = threadIdx.x;
    int v = dbin[i];
    int lane = i & 63, wave = i >> 6;
    int inc = v;
    #pragma unroll
    for (int off=1; off<64; off<<=1){
      int n = __shfl_up(inc, off);
      if (lane >= off) inc += n;
    }
    __shared__ int wsum[4];
    if (lane == 63) wsum[wave] = inc;
    __syncthreads();
    int wpre = 0;
    #pragma unroll
    for (int w=0; w<4; w++) if (w < wave) wpre += wsum[w];
    int run = wpre + inc - v;
    for (int blk=0; blk<SCAN_NBLK; blk++){
      colbase[(unsigned)blk*256 + i] = run;
      run += bcount[(unsigned)blk*256 + i];
    }
    return;
  }
  int i = (blockIdx.x - HIST_NB - 1)*256 + threadIdx.x;
  if (i < N_NODES){
    int b = offsets[i], e = offsets[i+1];
    for (int p=b; p<e; p++) sorted_dst[p] = i;
  }
}

// ---------------- GEMM1 bf16: 64-row blocks, 8 waves (2 row x 4 head), fused edot1 ----------------
__global__ __launch_bounds__(512) void k_gemm1f(
    const unsigned short* __restrict__ A, const unsigned short* __restrict__ Bt,
    const float* __restrict__ a1s, const float* __restrict__ a1d,
    unsigned short* __restrict__ Cbf, float* __restrict__ es, float* __restrict__ ed){
  const int K = 256, Nc = F1;
  int tid = threadIdx.x;
  int wave = tid>>6, lane = tid&63;
  int wr = wave>>2, wc = wave&3;   // wc = head
  int row0 = blockIdx.x*64 + wr*32;
  int col0 = wc*64;
  int lrow = lane&15, lk = (lane>>4)*8;
  f32x4 acc[2][4] = {};
  bf16x8 aA[2], bA[4], aB[2], bB[4];
  auto LOADF = [&](bf16x8* av, bf16x8* bv, int KS){
    #pragma unroll
    for (int i=0;i<2;i++)
      av[i] = *(const bf16x8*)(A  + (unsigned)(row0 + i*16 + lrow)*K + KS + lk);
    #pragma unroll
    for (int j=0;j<4;j++)
      bv[j] = *(const bf16x8*)(Bt + (unsigned)(col0 + j*16 + lrow)*K + KS + lk);
  };
  auto MFMAS = [&](bf16x8* av, bf16x8* bv){
    #pragma unroll
    for (int i=0;i<2;i++)
      #pragma unroll
      for (int j=0;j<4;j++)
        acc[i][j] = __builtin_amdgcn_mfma_f32_16x16x32_bf16(av[i], bv[j], acc[i][j], 0,0,0);
  };
  LOADF(aA,bA,0);
  #pragma unroll
  for (int ks=0; ks<K; ks+=64){
    LOADF(aB,bB,ks+32);
    MFMAS(aA,bA);
    if (ks+64 < K) LOADF(aA,bA,ks+64);
    MFMAS(aB,bB);
  }
  int crow = (lane>>4)*4, ccol = lane&15;
  #pragma unroll
  for (int i=0;i<2;i++)
    #pragma unroll
    for (int j=0;j<4;j++)
      #pragma unroll
      for (int q=0;q<4;q++){
        int r = row0 + i*16 + crow + q;
        int c = col0 + j*16 + ccol;
        Cbf[(unsigned)r*Nc + c] = f2b(acc[i][j][q]);
      }
  float avs[4], avd[4];
  #pragma unroll
  for (int j=0;j<4;j++){
    avs[j] = a1s[wc*64 + j*16 + ccol];
    avd[j] = a1d[wc*64 + j*16 + ccol];
  }
  #pragma unroll
  for (int i=0;i<2;i++){
    #pragma unroll
    for (int q=0;q<4;q++){
      float ps = acc[i][0][q]*avs[0] + acc[i][1][q]*avs[1] + acc[i][2][q]*avs[2] + acc[i][3][q]*avs[3];
      float pd = acc[i][0][q]*avd[0] + acc[i][1][q]*avd[1] + acc[i][2][q]*avd[2] + acc[i][3][q]*avd[3];
      #pragma unroll
      for (int off=1; off<16; off<<=1){ ps += __shfl_xor(ps,off); pd += __shfl_xor(pd,off); }
      if ((lane&15)==0){
        int r = row0 + i*16 + crow + q;
        es[(unsigned)r*4 + wc] = ps;
        ed[(unsigned)r*4 + wc] = pd;
      }
    }
  }
}

// ---------------- mid2: dscatter | eexp1 in ONE launch ----------------
__global__ __launch_bounds__(256) void k_mid2(
    const int* __restrict__ counts, const int* __restrict__ colbase, int* __restrict__ perm,
    const int* __restrict__ ssrc, const int* __restrict__ sdst,
    const float* __restrict__ es, const float* __restrict__ ed, float* __restrict__ ex){
  if (blockIdx.x < SCAN_NBLK){
    __shared__ int h[256];
    h[threadIdx.x] = 0;
    __syncthreads();
    int i = blockIdx.x*256 + threadIdx.x;
    if (i < N_NODES){
      int b = counts[i]; if (b > 255) b = 255;
      int r = atomicAdd(&h[b], 1);
      perm[colbase[(unsigned)blockIdx.x*256 + b] + r] = i;
    }
    return;
  }
  int e = (blockIdx.x - SCAN_NBLK)*256 + threadIdx.x;
  if (e >= EP) return;
  unsigned s = (unsigned)ssrc[e], d = (unsigned)sdst[e];
  float4 ev = *(const float4*)(es + s*4);
  float4 dv = *(const float4*)(ed + d*4);
  float4 o;
  o.x = __expf(leaky(ev.x+dv.x));
  o.y = __expf(leaky(ev.y+dv.y));
  o.z = __expf(leaky(ev.z+dv.z));
  o.w = __expf(leaky(ev.w+dv.w));
  *(float4*)(ex + (unsigned)e*4) = o;
}

// ---------------- GEMM2 bf16: 128-row blocks, 8 waves (4 row x 2 col) + fused edot2 ----------------
__global__ __launch_bounds__(512) void k_gemm2e(
    const unsigned short* __restrict__ A, const unsigned short* __restrict__ Bt,
    const float* __restrict__ a2s, const float* __restrict__ a2d,
    unsigned short* __restrict__ Cbf, float* __restrict__ es, float* __restrict__ ed){
  const int K = 256, Nc = F2;
  int tid = threadIdx.x;
  int wave = tid>>6, lane = tid&63;
  int wr = wave>>1, wc = wave&1;
  int row0 = blockIdx.x*128 + wr*32;
  int col0 = wc*64;
  int lrow = lane&15, lk = (lane>>4)*8;
  f32x4 acc[2][4] = {};
  bf16x8 aA[2], bA[4], aB[2], bB[4];
  auto LOADF = [&](bf16x8* av, bf16x8* bv, int KS){
    #pragma unroll
    for (int i=0;i<2;i++)
      av[i] = *(const bf16x8*)(A  + (unsigned)(row0 + i*16 + lrow)*K + KS + lk);
    #pragma unroll
    for (int j=0;j<4;j++)
      bv[j] = *(const bf16x8*)(Bt + (unsigned)(col0 + j*16 + lrow)*K + KS + lk);
  };
  auto MFMAS = [&](bf16x8* av, bf16x8* bv){
    #pragma unroll
    for (int i=0;i<2;i++)
      #pragma unroll
      for (int j=0;j<4;j++)
        acc[i][j] = __builtin_amdgcn_mfma_f32_16x16x32_bf16(av[i], bv[j], acc[i][j], 0,0,0);
  };
  LOADF(aA,bA,0);
  #pragma unroll
  for (int ks=0; ks<K; ks+=64){
    LOADF(aB,bB,ks+32);
    MFMAS(aA,bA);
    if (ks+64 < K) LOADF(aA,bA,ks+64);
    MFMAS(aB,bB);
  }
  int crow = (lane>>4)*4, ccol = lane&15;
  #pragma unroll
  for (int i=0;i<2;i++)
    #pragma unroll
    for (int j=0;j<4;j++)
      #pragma unroll
      for (int q=0;q<4;q++){
        int r = row0 + i*16 + crow + q;
        int c = col0 + j*16 + ccol;
        Cbf[(unsigned)r*Nc + c] = f2b(acc[i][j][q]);
      }
  __shared__ float ls[2][128];
  __shared__ float ldd[2][128];
  float avs[4], avd[4];
  #pragma unroll
  for (int j=0;j<4;j++){
    avs[j] = a2s[col0 + j*16 + ccol];
    avd[j] = a2d[col0 + j*16 + ccol];
  }
  #pragma unroll
  for (int i=0;i<2;i++){
    #pragma unroll
    for (int q=0;q<4;q++){
      float ps = acc[i][0][q]*avs[0] + acc[i][1][q]*avs[1] + acc[i][2][q]*avs[2] + acc[i][3][q]*avs[3];
      float pd = acc[i][0][q]*avd[0] + acc[i][1][q]*avd[1] + acc[i][2][q]*avd[2] + acc[i][3][q]*avd[3];
      #pragma unroll
      for (int off=1; off<16; off<<=1){ ps += __shfl_xor(ps,off); pd += __shfl_xor(pd,off); }
      if ((lane&15)==0){
        int rb = wr*32 + i*16 + crow + q;
        ls[wc][rb] = ps;
        ldd[wc][rb] = pd;
      }
    }
  }
  __syncthreads();
  int t = tid;
  if (t < 128){
    int n = blockIdx.x*128 + t;
    if (n < N_NODES){
      es[n] = ls[0][t] + ls[1][t];
      ed[n] = ldd[0][t] + ldd[1][t];
    }
  }
}

// ---------------- eexp2 ----------------
__global__ __launch_bounds__(256) void k_eexp2(const int* __restrict__ ssrc, const int* __restrict__ sdst,
                        const float* __restrict__ es, const float* __restrict__ ed,
                        float* __restrict__ ex){
  int e = blockIdx.x*256 + threadIdx.x;
  if (e >= EP) return;
  unsigned s = (unsigned)ssrc[e], d = (unsigned)sdst[e];
  ex[e] = __expf(leaky(es[s] + ed[d]));
}

// ---------------- layer-1 aggregation ----------------
__global__ __launch_bounds__(256) void k_agg1(const unsigned short* __restrict__ h1bf, const float* __restrict__ ex1,
                       const int* __restrict__ offsets,
                       const int* __restrict__ ssrc, const int* __restrict__ perm,
                       const float* __restrict__ b1,
                       unsigned short* __restrict__ A2hi){
  int wave = threadIdx.x>>6, lane = threadIdx.x&63;
  int idx = blockIdx.x*4 + wave;
  if (idx >= M_PAD) return;
  if (idx >= N_NODES){
    ushort4 z = {0,0,0,0};
    ((ushort4*)(A2hi + (unsigned)idx*F1))[lane] = z;
    return;
  }
  int d = perm[idx];
  unsigned beg = (unsigned)offsets[d], end = (unsigned)offsets[d+1];
  unsigned deg = end - beg;
  unsigned head = (unsigned)(lane>>4);
  const ushort4* __restrict__ hb = (const ushort4*)h1bf;
  const float* __restrict__ exh = ex1 + head;
  float s0=0.f,s1=0.f,s2=0.f,s3=0.f;
  float4 acc0={0,0,0,0}, acc1={0,0,0,0}, acc2={0,0,0,0}, acc3={0,0,0,0};
  unsigned j=0;
  for (; j+4<=deg; j+=4){
    unsigned e0=beg+j;
    unsigned sn0=(unsigned)ssrc[e0], sn1=(unsigned)ssrc[e0+1], sn2=(unsigned)ssrc[e0+2], sn3=(unsigned)ssrc[e0+3];
    float x0 = exh[e0*4], x1 = exh[e0*4+4], x2 = exh[e0*4+8], x3 = exh[e0*4+12];
    ushort4 v0 = hb[sn0*64 + lane];
    ushort4 v1 = hb[sn1*64 + lane];
    ushort4 v2 = hb[sn2*64 + lane];
    ushort4 v3 = hb[sn3*64 + lane];
    s0+=x0; s1+=x1; s2+=x2; s3+=x3;
    acc0.x=fmaf(x0,b2f(v0.x),acc0.x); acc0.y=fmaf(x0,b2f(v0.y),acc0.y); acc0.z=fmaf(x0,b2f(v0.z),acc0.z); acc0.w=fmaf(x0,b2f(v0.w),acc0.w);
    acc1.x=fmaf(x1,b2f(v1.x),acc1.x); acc1.y=fmaf(x1,b2f(v1.y),acc1.y); acc1.z=fmaf(x1,b2f(v1.z),acc1.z); acc1.w=fmaf(x1,b2f(v1.w),acc1.w);
    acc2.x=fmaf(x2,b2f(v2.x),acc2.x); acc2.y=fmaf(x2,b2f(v2.y),acc2.y); acc2.z=fmaf(x2,b2f(v2.z),acc2.z); acc2.w=fmaf(x2,b2f(v2.w),acc2.w);
    acc3.x=fmaf(x3,b2f(v3.x),acc3.x); acc3.y=fmaf(x3,b2f(v3.y),acc3.y); acc3.z=fmaf(x3,b2f(v3.z),acc3.z); acc3.w=fmaf(x3,b2f(v3.w),acc3.w);
  }
  for (; j<deg; j++){
    unsigned e0=beg+j;
    unsigned sn=(unsigned)ssrc[e0];
    float x = exh[e0*4];
    ushort4 v = hb[sn*64 + lane];
    s0 += x;
    acc0.x=fmaf(x,b2f(v.x),acc0.x); acc0.y=fmaf(x,b2f(v.y),acc0.y);
    acc0.z=fmaf(x,b2f(v.z),acc0.z); acc0.w=fmaf(x,b2f(v.w),acc0.w);
  }
  float inv = 1.f/(s0+s1+s2+s3+1e-16f);
  float4 acc;
  acc.x = (acc0.x+acc1.x+acc2.x+acc3.x)*inv;
  acc.y = (acc0.y+acc1.y+acc2.y+acc3.y)*inv;
  acc.z = (acc0.z+acc1.z+acc2.z+acc3.z)*inv;
  acc.w = (acc0.w+acc1.w+acc2.w+acc3.w)*inv;
  float4 bb = *(const float4*)(b1 + lane*4);
  ushort4 hi;
  hi.x = f2b(elu_f(acc.x + bb.x));
  hi.y = f2b(elu_f(acc.y + bb.y));
  hi.z = f2b(elu_f(acc.z + bb.z));
  hi.w = f2b(elu_f(acc.w + bb.w));
  ((ushort4*)(A2hi + (unsigned)d*F1))[lane] = hi;
}

// ---------------- layer-2 aggregation + final mean (unroll 8) ----------------
__global__ __launch_bounds__(256) void k_agg2(const unsigned short* __restrict__ h2bf, const float* __restrict__ ex2,
                       const int* __restrict__ offsets,
                       const int* __restrict__ ssrc, const int* __restrict__ perm,
                       const float* __restrict__ b2, float* __restrict__ out){
  int wave=threadIdx.x>>6, lane=threadIdx.x&63;
  int idx = blockIdx.x*4+wave; if (idx>=N_NODES) return;
  int d = perm[idx];
  unsigned beg=(unsigned)offsets[d], end=(unsigned)offsets[d+1];
  unsigned deg=end-beg;
  const ushort2* __restrict__ hb = (const ushort2*)h2bf;
  float s0=0.f,s1=0.f,s2=0.f,s3=0.f;
  float2 acc0={0,0}, acc1={0,0}, acc2={0,0}, acc3={0,0};
  unsigned j=0;
  for (; j+8<=deg; j+=8){
    unsigned e0=beg+j;
    unsigned sn[8]; float xx[8]; ushort2 vv[8];
    #pragma unroll
    for (int u=0;u<8;u++) sn[u]=(unsigned)ssrc[e0+u];
    #pragma unroll
    for (int u=0;u<8;u++){ xx[u]=ex2[e0+u]; vv[u]=hb[sn[u]*64 + lane]; }
    s0+=xx[0]+xx[4]; s1+=xx[1]+xx[5]; s2+=xx[2]+xx[6]; s3+=xx[3]+xx[7];
    #pragma unroll
    for (int u=0;u<8;u++){
      float2* ac = (u&3)==0?&acc0:((u&3)==1?&acc1:((u&3)==2?&acc2:&acc3));
      ac->x=fmaf(xx[u],b2f(vv[u].x),ac->x); ac->y=fmaf(xx[u],b2f(vv[u].y),ac->y);
    }
  }
  for (; j<deg; j++){
    unsigned e0=beg+j;
    unsigned sn=(unsigned)ssrc[e0];
    float x = ex2[e0];
    ushort2 v = hb[sn*64 + lane];
    s0 += x;
    acc0.x=fmaf(x,b2f(v.x),acc0.x); acc0.y=fmaf(x,b2f(v.y),acc0.y);
  }
  float inv = 1.f/(s0+s1+s2+s3+1e-16f);
  float2 acc;
  acc.x = (acc0.x+acc1.x+acc2.x+acc3.x)*inv;
  acc.y = (acc0.y+acc1.y+acc2.y+acc3.y)*inv;
  float2 bb = *(const float2*)(b2 + lane*2);
  float r = elu_f(acc.x+bb.x) + elu_f(acc.y+bb.y);
  #pragma unroll
  for (int off=1;off<64;off<<=1) r += __shfl_xor(r,off);
  if (lane==0) out[d] = r * (1.f/128.f);
}

extern "C" void kernel_launch(void* const* d_in, const int* in_sizes, int n_in,
                              void* d_out, int out_size, void* d_ws, size_t ws_size,
                              hipStream_t stream) {
  const float* x   = (const float*)d_in[0];
  const int*   ei  = (const int*)d_in[1];
  const int*   esrc = ei;
  const int*   edst = ei + N_EDGES;
  const float* W1  = (const float*)d_in[2];
  const float* a1s = (const float*)d_in[3];
  const float* a1d = (const float*)d_in[4];
  const float* b1  = (const float*)d_in[5];
  const float* W2  = (const float*)d_in[6];
  const float* a2s = (const float*)d_in[7];
  const float* a2d = (const float*)d_in[8];
  const float* b2  = (const float*)d_in[9];
  float* out = (float*)d_out;

  char* ws = (char*)d_ws;
  size_t off = 0;
  auto alloc = [&](size_t bytes)->void*{ void* p = ws + off; off += (bytes + 255) & ~(size_t)255; return p; };
  unsigned short* A1hi = (unsigned short*)alloc((size_t)M_PAD*F1*2);
  unsigned short* h1bf = (unsigned short*)alloc((size_t)M_PAD*F1*2);
  unsigned short* h2bf = (unsigned short*)alloc((size_t)M_PAD*F2*2);
  unsigned short* Bt1hi= (unsigned short*)alloc((size_t)F1*DIN*2);
  unsigned short* Bt2hi= (unsigned short*)alloc((size_t)F2*F1*2);
  float* e1s   = (float*)alloc((size_t)M_PAD*HEADS*4);
  float* e1d   = (float*)alloc((size_t)M_PAD*HEADS*4);
  float* e2s   = (float*)alloc((size_t)N_NODES*4);
  float* e2d   = (float*)alloc((size_t)N_NODES*4);
  float* ex1   = (float*)alloc((size_t)EP*HEADS*4);
  float* ex2   = (float*)alloc((size_t)EP*4);
  int*   counts= (int*)alloc((size_t)N_NODES*4);
  int*   offs  = (int*)alloc((size_t)(N_NODES+1)*4);
  int*   rank  = (int*)alloc((size_t)EP*4);
  int*   exc   = (int*)alloc((size_t)N_NODES*4);
  int*   bsum  = (int*)alloc((size_t)SCAN_NBLK*4);
  int*   perm  = (int*)alloc((size_t)N_NODES*4);
  int*   dbin  = (int*)alloc((size_t)256*4);
  int*   bcount= (int*)alloc((size_t)SCAN_NBLK*256*4);
  int*   colbase=(int*)alloc((size_t)SCAN_NBLK*256*4);
  int*   ssrc  = (int*)alloc((size_t)EP*4);
  int*   sdst  = (int*)alloc((size_t)EP*4);
  unsigned short* A2hi = A1hi;   // layer-1 input dead after gemm1

  hipMemsetAsync(counts, 0, (size_t)N_NODES*4, stream);
  k_prep<<<SA_NB + WT_NB + HIST_NB, 256, 0, stream>>>(x, A1hi, W1, W2, Bt1hi, Bt2hi, edst, counts, rank);
  k_scan1<<<SCAN_NBLK, 256, 0, stream>>>(counts, exc, bsum, dbin);
  k_scan3d<<<SCAN_NBLK, 256, 0, stream>>>(exc, bsum, counts, offs, dbin, bcount);
  k_scatter_dcol_fill<<<HIST_NB + 1 + SCAN_NBLK, 256, 0, stream>>>(esrc, edst, rank, ssrc, sdst,
                                                                   dbin, bcount, colbase, offs);
  k_gemm1f<<<GEMM1_NB, 512, 0, stream>>>(A1hi, Bt1hi, a1s, a1d, h1bf, e1s, e1d);
  k_mid2<<<SCAN_NBLK + HIST_NB, 256, 0, stream>>>(counts, colbase, perm, ssrc, sdst, e1s, e1d, ex1);
  k_agg1<<<(M_PAD+3)/4, 256, 0, stream>>>(h1bf, ex1, offs, ssrc, perm, b1, A2hi);

  k_gemm2e<<<M_PAD/128, 512, 0, stream>>>(A2hi, Bt2hi, a2s, a2d, h2bf, e2s, e2d);
  k_eexp2<<<HIST_NB, 256, 0, stream>>>(ssrc, sdst, e2s, e2d, ex2);
  k_agg2<<<(N_NODES+3)/4, 256, 0, stream>>>(h2bf, ex2, offs, ssrc, perm, b2, out);
}

// Round 16
// 263.262 us; speedup vs baseline: 1.0481x; 1.0481x over previous
//
#include <hip/hip_runtime.h>
#include <math.h>

#define N_NODES 50000
#define M_PAD   50048            /* 391*128 = 782*64 */
#define N_EDGES 800000
#define EP (N_EDGES + N_NODES)
#define DIN 256
#define HEADS 4
#define HID 64
#define F1 256
#define F2 128
#define NEG_SLOPE 0.2f
#define SCAN_NBLK ((N_NODES + 255)/256)   /* 196 */
#define HIST_NB ((EP + 255)/256)          /* 3321 */
#define SA_NB (M_PAD*F1/4/256)            /* 12512 */
#define WT_TOT (DIN*F1 + F1*F2)
#define WT_NB ((WT_TOT + 255)/256)        /* 384 */
#define GEMM1_NB (M_PAD/64)               /* 782 */

typedef short bf16x8 __attribute__((ext_vector_type(8)));
typedef float f32x4  __attribute__((ext_vector_type(4)));

static __device__ __forceinline__ float leaky(float x){ return x > 0.f ? x : NEG_SLOPE*x; }
static __device__ __forceinline__ float elu_f(float x){ return x > 0.f ? x : (__expf(x)-1.f); }
static __device__ __forceinline__ float b2f(unsigned short u){ return __uint_as_float(((unsigned)u)<<16); }
static __device__ __forceinline__ unsigned short f2b(float f){
  unsigned u = __float_as_uint(f);
  return (unsigned short)((u + 0x7fffu + ((u>>16)&1u)) >> 16);   // RNE
}

// ---------------- fused prep: splitA | splitWT(W1,W2) | edge histogram (+rank) ----------------
__global__ __launch_bounds__(256) void k_prep(const float* __restrict__ X, unsigned short* __restrict__ Ahi,
    const float* __restrict__ W1, const float* __restrict__ W2,
    unsigned short* __restrict__ Bt1, unsigned short* __restrict__ Bt2,
    const int* __restrict__ dst, int* __restrict__ counts, int* __restrict__ rank){
  unsigned b = blockIdx.x;
  if (b < SA_NB){
    int gid = b*256 + threadIdx.x;
    size_t base = (size_t)gid*4;
    int row = (int)(base >> 8);
    ushort4 hi;
    if (row < N_NODES){
      float4 v = *(const float4*)(X + base);
      hi.x=f2b(v.x); hi.y=f2b(v.y); hi.z=f2b(v.z); hi.w=f2b(v.w);
    } else {
      hi = {0,0,0,0};
    }
    *(ushort4*)(Ahi + base) = hi;
  } else if (b < SA_NB + WT_NB){
    int t = (b - SA_NB)*256 + threadIdx.x;
    if (t < DIN*F1){
      int n = t / DIN, k = t % DIN;
      Bt1[(unsigned)n*DIN + k] = f2b(W1[(unsigned)k*F1 + n]);
    } else if (t < WT_TOT){
      int u = t - DIN*F1;
      int n = u / F1, k = u % F1;
      Bt2[(unsigned)n*F1 + k] = f2b(W2[(unsigned)k*F2 + n]);
    }
  } else {
    int e = (b - SA_NB - WT_NB)*256 + threadIdx.x;
    if (e < EP){
      int d = (e < N_EDGES) ? dst[e] : (e - N_EDGES);
      rank[e] = atomicAdd(&counts[d], 1);
    }
  }
}

// ---------------- scan level 1 (+ zero dbin in block 0) ----------------
__global__ __launch_bounds__(256) void k_scan1(const int* __restrict__ counts,
                                               int* __restrict__ exc, int* __restrict__ bsum,
                                               int* __restrict__ dbin){
  if (blockIdx.x == 0) dbin[threadIdx.x] = 0;
  int i = blockIdx.x*256 + threadIdx.x;
  int v = (i < N_NODES) ? counts[i] : 0;
  int lane = threadIdx.x & 63, wave = threadIdx.x >> 6;
  int inc = v;
  #pragma unroll
  for (int off=1; off<64; off<<=1){
    int n = __shfl_up(inc, off);
    if (lane >= off) inc += n;
  }
  __shared__ int wsum[4];
  if (lane == 63) wsum[wave] = inc;
  __syncthreads();
  int wpre = 0;
  #pragma unroll
  for (int w=0; w<4; w++) if (w < wave) wpre += wsum[w];
  if (i < N_NODES) exc[i] = wpre + inc - v;
  if (threadIdx.x == 255) bsum[blockIdx.x] = wpre + inc;
}

// ---------------- scan3d: inline block-prefix + offsets + degree histogram ----------------
__global__ __launch_bounds__(256) void k_scan3d(const int* __restrict__ exc, const int* __restrict__ bsum,
                                                const int* __restrict__ counts,
                                                int* __restrict__ offsets,
                                                int* __restrict__ dbin, int* __restrict__ bcount){
  int t = threadIdx.x;
  int lane = t & 63, wave = t >> 6;
  int v = (t < (int)blockIdx.x) ? bsum[t] : 0;
  #pragma unroll
  for (int off=1; off<64; off<<=1) v += __shfl_xor(v, off);
  __shared__ int ws[4];
  __shared__ int hh[256];
  if (lane == 0) ws[wave] = v;
  hh[t] = 0;
  __syncthreads();
  int bpref = ws[0] + ws[1] + ws[2] + ws[3];
  int i = blockIdx.x*256 + t;
  if (i < N_NODES){
    int o = exc[i] + bpref;
    offsets[i] = o;
    int b = counts[i]; if (b > 255) b = 255;
    atomicAdd(&hh[b], 1);
  }
  if (i == 0) offsets[N_NODES] = EP;
  __syncthreads();
  int c = hh[t];
  bcount[(unsigned)blockIdx.x*256 + t] = c;
  if (c) atomicAdd(&dbin[t], c);
}

// ---------------- scatter (atomic-free, via rank) | dcol | node-major sdst fill ----------------
__global__ __launch_bounds__(256) void k_scatter_dcol_fill(
    const int* __restrict__ src, const int* __restrict__ dst, const int* __restrict__ rank,
    int* __restrict__ sorted_src, int* __restrict__ sorted_dst,
    const int* __restrict__ dbin, const int* __restrict__ bcount, int* __restrict__ colbase,
    const int* __restrict__ offsets){
  if (blockIdx.x < HIST_NB){
    int e = blockIdx.x*256 + threadIdx.x;
    if (e >= EP) return;
    int s, d;
    if (e < N_EDGES){ s = src[e]; d = dst[e]; } else { s = d = e - N_EDGES; }
    int pos = offsets[d] + rank[e];
    sorted_src[pos] = s;
    return;
  }
  if (blockIdx.x == HIST_NB){
    int i = threadIdx.x;
    int v = dbin[i];
    int lane = i & 63, wave = i >> 6;
    int inc = v;
    #pragma unroll
    for (int off=1; off<64; off<<=1){
      int n = __shfl_up(inc, off);
      if (lane >= off) inc += n;
    }
    __shared__ int wsum[4];
    if (lane == 63) wsum[wave] = inc;
    __syncthreads();
    int wpre = 0;
    #pragma unroll
    for (int w=0; w<4; w++) if (w < wave) wpre += wsum[w];
    int run = wpre + inc - v;
    for (int blk=0; blk<SCAN_NBLK; blk++){
      colbase[(unsigned)blk*256 + i] = run;
      run += bcount[(unsigned)blk*256 + i];
    }
    return;
  }
  int i = (blockIdx.x - HIST_NB - 1)*256 + threadIdx.x;
  if (i < N_NODES){
    int b = offsets[i], e = offsets[i+1];
    for (int p=b; p<e; p++) sorted_dst[p] = i;
  }
}

// ---------------- GEMM1 bf16 (64-row blocks, WC=4 heads) + fused edot1 ----------------
__global__ __launch_bounds__(256) void k_gemm1f(
    const unsigned short* __restrict__ A, const unsigned short* __restrict__ Bt,
    const float* __restrict__ a1s, const float* __restrict__ a1d,
    unsigned short* __restrict__ Cbf, float* __restrict__ es, float* __restrict__ ed){
  const int K = 256, Nc = F1;
  int tid = threadIdx.x;
  int wave = tid>>6, lane = tid&63;
  int wc = wave;                 // head
  int row0 = blockIdx.x*64;
  int col0 = wc*64;
  int lrow = lane&15, lk = (lane>>4)*8;
  f32x4 acc[4][4] = {};
  bf16x8 aA[4], bA[4], aB[4], bB[4];
  auto LOADF = [&](bf16x8* av, bf16x8* bv, int KS){
    #pragma unroll
    for (int i=0;i<4;i++){
      av[i] = *(const bf16x8*)(A  + (unsigned)(row0 + i*16 + lrow)*K + KS + lk);
      bv[i] = *(const bf16x8*)(Bt + (unsigned)(col0 + i*16 + lrow)*K + KS + lk);
    }
  };
  auto MFMAS = [&](bf16x8* av, bf16x8* bv){
    #pragma unroll
    for (int i=0;i<4;i++)
      #pragma unroll
      for (int j=0;j<4;j++)
        acc[i][j] = __builtin_amdgcn_mfma_f32_16x16x32_bf16(av[i], bv[j], acc[i][j], 0,0,0);
  };
  LOADF(aA,bA,0);
  #pragma unroll
  for (int ks=0; ks<K; ks+=64){
    LOADF(aB,bB,ks+32);
    MFMAS(aA,bA);
    if (ks+64 < K) LOADF(aA,bA,ks+64);
    MFMAS(aB,bB);
  }
  int crow = (lane>>4)*4, ccol = lane&15;
  #pragma unroll
  for (int i=0;i<4;i++)
    #pragma unroll
    for (int j=0;j<4;j++)
      #pragma unroll
      for (int q=0;q<4;q++){
        int r = row0 + i*16 + crow + q;
        int c = col0 + j*16 + ccol;
        Cbf[(unsigned)r*Nc + c] = f2b(acc[i][j][q]);
      }
  float avs[4], avd[4];
  #pragma unroll
  for (int j=0;j<4;j++){
    avs[j] = a1s[wc*64 + j*16 + ccol];
    avd[j] = a1d[wc*64 + j*16 + ccol];
  }
  #pragma unroll
  for (int i=0;i<4;i++){
    #pragma unroll
    for (int q=0;q<4;q++){
      float ps = acc[i][0][q]*avs[0] + acc[i][1][q]*avs[1] + acc[i][2][q]*avs[2] + acc[i][3][q]*avs[3];
      float pd = acc[i][0][q]*avd[0] + acc[i][1][q]*avd[1] + acc[i][2][q]*avd[2] + acc[i][3][q]*avd[3];
      #pragma unroll
      for (int off=1; off<16; off<<=1){ ps += __shfl_xor(ps,off); pd += __shfl_xor(pd,off); }
      if ((lane&15)==0){
        int r = row0 + i*16 + crow + q;
        es[(unsigned)r*4 + wc] = ps;
        ed[(unsigned)r*4 + wc] = pd;
      }
    }
  }
}

// ---------------- mid2: dscatter | eexp1 in ONE launch ----------------
__global__ __launch_bounds__(256) void k_mid2(
    const int* __restrict__ counts, const int* __restrict__ colbase, int* __restrict__ perm,
    const int* __restrict__ ssrc, const int* __restrict__ sdst,
    const float* __restrict__ es, const float* __restrict__ ed, float* __restrict__ ex){
  if (blockIdx.x < SCAN_NBLK){
    __shared__ int h[256];
    h[threadIdx.x] = 0;
    __syncthreads();
    int i = blockIdx.x*256 + threadIdx.x;
    if (i < N_NODES){
      int b = counts[i]; if (b > 255) b = 255;
      int r = atomicAdd(&h[b], 1);
      perm[colbase[(unsigned)blockIdx.x*256 + b] + r] = i;
    }
    return;
  }
  int e = (blockIdx.x - SCAN_NBLK)*256 + threadIdx.x;
  if (e >= EP) return;
  unsigned s = (unsigned)ssrc[e], d = (unsigned)sdst[e];
  float4 ev = *(const float4*)(es + s*4);
  float4 dv = *(const float4*)(ed + d*4);
  float4 o;
  o.x = __expf(leaky(ev.x+dv.x));
  o.y = __expf(leaky(ev.y+dv.y));
  o.z = __expf(leaky(ev.z+dv.z));
  o.w = __expf(leaky(ev.w+dv.w));
  *(float4*)(ex + (unsigned)e*4) = o;
}

// ---------------- GEMM2 bf16 (128-row blocks, 2x2 waves) + fused edot2 ----------------
__global__ __launch_bounds__(256) void k_gemm2e(
    const unsigned short* __restrict__ A, const unsigned short* __restrict__ Bt,
    const float* __restrict__ a2s, const float* __restrict__ a2d,
    unsigned short* __restrict__ Cbf, float* __restrict__ es, float* __restrict__ ed){
  const int K = 256, Nc = F2;
  int tid = threadIdx.x;
  int wave = tid>>6, lane = tid&63;
  int wr = wave>>1, wc = wave&1;
  int row0 = blockIdx.x*128 + wr*64;
  int col0 = wc*64;
  int lrow = lane&15, lk = (lane>>4)*8;
  f32x4 acc[4][4] = {};
  bf16x8 aA[4], bA[4], aB[4], bB[4];
  auto LOADF = [&](bf16x8* av, bf16x8* bv, int KS){
    #pragma unroll
    for (int i=0;i<4;i++){
      av[i] = *(const bf16x8*)(A  + (unsigned)(row0 + i*16 + lrow)*K + KS + lk);
      bv[i] = *(const bf16x8*)(Bt + (unsigned)(col0 + i*16 + lrow)*K + KS + lk);
    }
  };
  auto MFMAS = [&](bf16x8* av, bf16x8* bv){
    #pragma unroll
    for (int i=0;i<4;i++)
      #pragma unroll
      for (int j=0;j<4;j++)
        acc[i][j] = __builtin_amdgcn_mfma_f32_16x16x32_bf16(av[i], bv[j], acc[i][j], 0,0,0);
  };
  LOADF(aA,bA,0);
  #pragma unroll
  for (int ks=0; ks<K; ks+=64){
    LOADF(aB,bB,ks+32);
    MFMAS(aA,bA);
    if (ks+64 < K) LOADF(aA,bA,ks+64);
    MFMAS(aB,bB);
  }
  int crow = (lane>>4)*4, ccol = lane&15;
  #pragma unroll
  for (int i=0;i<4;i++)
    #pragma unroll
    for (int j=0;j<4;j++)
      #pragma unroll
      for (int q=0;q<4;q++){
        int r = row0 + i*16 + crow + q;
        int c = col0 + j*16 + ccol;
        Cbf[(unsigned)r*Nc + c] = f2b(acc[i][j][q]);
      }
  __shared__ float ls[2][128];
  __shared__ float ldd[2][128];
  float avs[4], avd[4];
  #pragma unroll
  for (int j=0;j<4;j++){
    avs[j] = a2s[col0 + j*16 + ccol];
    avd[j] = a2d[col0 + j*16 + ccol];
  }
  #pragma unroll
  for (int i=0;i<4;i++){
    #pragma unroll
    for (int q=0;q<4;q++){
      float ps = acc[i][0][q]*avs[0] + acc[i][1][q]*avs[1] + acc[i][2][q]*avs[2] + acc[i][3][q]*avs[3];
      float pd = acc[i][0][q]*avd[0] + acc[i][1][q]*avd[1] + acc[i][2][q]*avd[2] + acc[i][3][q]*avd[3];
      #pragma unroll
      for (int off=1; off<16; off<<=1){ ps += __shfl_xor(ps,off); pd += __shfl_xor(pd,off); }
      if ((lane&15)==0){
        int rb = wr*64 + i*16 + crow + q;
        ls[wc][rb] = ps;
        ldd[wc][rb] = pd;
      }
    }
  }
  __syncthreads();
  int t = tid;
  if (t < 128){
    int n = blockIdx.x*128 + t;
    if (n < N_NODES){
      es[n] = ls[0][t] + ls[1][t];
      ed[n] = ldd[0][t] + ldd[1][t];
    }
  }
}

// ---------------- eexp2 ----------------
__global__ __launch_bounds__(256) void k_eexp2(const int* __restrict__ ssrc, const int* __restrict__ sdst,
                        const float* __restrict__ es, const float* __restrict__ ed,
                        float* __restrict__ ex){
  int e = blockIdx.x*256 + threadIdx.x;
  if (e >= EP) return;
  unsigned s = (unsigned)ssrc[e], d = (unsigned)sdst[e];
  ex[e] = __expf(leaky(es[s] + ed[d]));
}

// ---------------- layer-1 aggregation ----------------
__global__ __launch_bounds__(256) void k_agg1(const unsigned short* __restrict__ h1bf, const float* __restrict__ ex1,
                       const int* __restrict__ offsets,
                       const int* __restrict__ ssrc, const int* __restrict__ perm,
                       const float* __restrict__ b1,
                       unsigned short* __restrict__ A2hi){
  int wave = threadIdx.x>>6, lane = threadIdx.x&63;
  int idx = blockIdx.x*4 + wave;
  if (idx >= M_PAD) return;
  if (idx >= N_NODES){
    ushort4 z = {0,0,0,0};
    ((ushort4*)(A2hi + (unsigned)idx*F1))[lane] = z;
    return;
  }
  int d = perm[idx];
  unsigned beg = (unsigned)offsets[d], end = (unsigned)offsets[d+1];
  unsigned deg = end - beg;
  unsigned head = (unsigned)(lane>>4);
  const ushort4* __restrict__ hb = (const ushort4*)h1bf;
  const float* __restrict__ exh = ex1 + head;
  float s0=0.f,s1=0.f,s2=0.f,s3=0.f;
  float4 acc0={0,0,0,0}, acc1={0,0,0,0}, acc2={0,0,0,0}, acc3={0,0,0,0};
  unsigned j=0;
  for (; j+4<=deg; j+=4){
    unsigned e0=beg+j;
    unsigned sn0=(unsigned)ssrc[e0], sn1=(unsigned)ssrc[e0+1], sn2=(unsigned)ssrc[e0+2], sn3=(unsigned)ssrc[e0+3];
    float x0 = exh[e0*4], x1 = exh[e0*4+4], x2 = exh[e0*4+8], x3 = exh[e0*4+12];
    ushort4 v0 = hb[sn0*64 + lane];
    ushort4 v1 = hb[sn1*64 + lane];
    ushort4 v2 = hb[sn2*64 + lane];
    ushort4 v3 = hb[sn3*64 + lane];
    s0+=x0; s1+=x1; s2+=x2; s3+=x3;
    acc0.x=fmaf(x0,b2f(v0.x),acc0.x); acc0.y=fmaf(x0,b2f(v0.y),acc0.y); acc0.z=fmaf(x0,b2f(v0.z),acc0.z); acc0.w=fmaf(x0,b2f(v0.w),acc0.w);
    acc1.x=fmaf(x1,b2f(v1.x),acc1.x); acc1.y=fmaf(x1,b2f(v1.y),acc1.y); acc1.z=fmaf(x1,b2f(v1.z),acc1.z); acc1.w=fmaf(x1,b2f(v1.w),acc1.w);
    acc2.x=fmaf(x2,b2f(v2.x),acc2.x); acc2.y=fmaf(x2,b2f(v2.y),acc2.y); acc2.z=fmaf(x2,b2f(v2.z),acc2.z); acc2.w=fmaf(x2,b2f(v2.w),acc2.w);
    acc3.x=fmaf(x3,b2f(v3.x),acc3.x); acc3.y=fmaf(x3,b2f(v3.y),acc3.y); acc3.z=fmaf(x3,b2f(v3.z),acc3.z); acc3.w=fmaf(x3,b2f(v3.w),acc3.w);
  }
  for (; j<deg; j++){
    unsigned e0=beg+j;
    unsigned sn=(unsigned)ssrc[e0];
    float x = exh[e0*4];
    ushort4 v = hb[sn*64 + lane];
    s0 += x;
    acc0.x=fmaf(x,b2f(v.x),acc0.x); acc0.y=fmaf(x,b2f(v.y),acc0.y);
    acc0.z=fmaf(x,b2f(v.z),acc0.z); acc0.w=fmaf(x,b2f(v.w),acc0.w);
  }
  float inv = 1.f/(s0+s1+s2+s3+1e-16f);
  float4 acc;
  acc.x = (acc0.x+acc1.x+acc2.x+acc3.x)*inv;
  acc.y = (acc0.y+acc1.y+acc2.y+acc3.y)*inv;
  acc.z = (acc0.z+acc1.z+acc2.z+acc3.z)*inv;
  acc.w = (acc0.w+acc1.w+acc2.w+acc3.w)*inv;
  float4 bb = *(const float4*)(b1 + lane*4);
  ushort4 hi;
  hi.x = f2b(elu_f(acc.x + bb.x));
  hi.y = f2b(elu_f(acc.y + bb.y));
  hi.z = f2b(elu_f(acc.z + bb.z));
  hi.w = f2b(elu_f(acc.w + bb.w));
  ((ushort4*)(A2hi + (unsigned)d*F1))[lane] = hi;
}

// ---------------- layer-2 aggregation + final mean ----------------
__global__ __launch_bounds__(256) void k_agg2(const unsigned short* __restrict__ h2bf, const float* __restrict__ ex2,
                       const int* __restrict__ offsets,
                       const int* __restrict__ ssrc, const int* __restrict__ perm,
                       const float* __restrict__ b2, float* __restrict__ out){
  int wave=threadIdx.x>>6, lane=threadIdx.x&63;
  int idx = blockIdx.x*4+wave; if (idx>=N_NODES) return;
  int d = perm[idx];
  unsigned beg=(unsigned)offsets[d], end=(unsigned)offsets[d+1];
  unsigned deg=end-beg;
  const ushort2* __restrict__ hb = (const ushort2*)h2bf;
  float s0=0.f,s1=0.f,s2=0.f,s3=0.f;
  float2 acc0={0,0}, acc1={0,0}, acc2={0,0}, acc3={0,0};
  unsigned j=0;
  for (; j+4<=deg; j+=4){
    unsigned e0=beg+j;
    unsigned sn0=(unsigned)ssrc[e0], sn1=(unsigned)ssrc[e0+1], sn2=(unsigned)ssrc[e0+2], sn3=(unsigned)ssrc[e0+3];
    float x0=ex2[e0], x1=ex2[e0+1], x2=ex2[e0+2], x3=ex2[e0+3];
    ushort2 v0 = hb[sn0*64 + lane];
    ushort2 v1 = hb[sn1*64 + lane];
    ushort2 v2 = hb[sn2*64 + lane];
    ushort2 v3 = hb[sn3*64 + lane];
    s0+=x0; s1+=x1; s2+=x2; s3+=x3;
    acc0.x=fmaf(x0,b2f(v0.x),acc0.x); acc0.y=fmaf(x0,b2f(v0.y),acc0.y);
    acc1.x=fmaf(x1,b2f(v1.x),acc1.x); acc1.y=fmaf(x1,b2f(v1.y),acc1.y);
    acc2.x=fmaf(x2,b2f(v2.x),acc2.x); acc2.y=fmaf(x2,b2f(v2.y),acc2.y);
    acc3.x=fmaf(x3,b2f(v3.x),acc3.x); acc3.y=fmaf(x3,b2f(v3.y),acc3.y);
  }
  for (; j<deg; j++){
    unsigned e0=beg+j;
    unsigned sn=(unsigned)ssrc[e0];
    float x = ex2[e0];
    ushort2 v = hb[sn*64 + lane];
    s0 += x;
    acc0.x=fmaf(x,b2f(v.x),acc0.x); acc0.y=fmaf(x,b2f(v.y),acc0.y);
  }
  float inv = 1.f/(s0+s1+s2+s3+1e-16f);
  float2 acc;
  acc.x = (acc0.x+acc1.x+acc2.x+acc3.x)*inv;
  acc.y = (acc0.y+acc1.y+acc2.y+acc3.y)*inv;
  float2 bb = *(const float2*)(b2 + lane*2);
  float r = elu_f(acc.x+bb.x) + elu_f(acc.y+bb.y);
  #pragma unroll
  for (int off=1;off<64;off<<=1) r += __shfl_xor(r,off);
  if (lane==0) out[d] = r * (1.f/128.f);
}

extern "C" void kernel_launch(void* const* d_in, const int* in_sizes, int n_in,
                              void* d_out, int out_size, void* d_ws, size_t ws_size,
                              hipStream_t stream) {
  const float* x   = (const float*)d_in[0];
  const int*   ei  = (const int*)d_in[1];
  const int*   esrc = ei;
  const int*   edst = ei + N_EDGES;
  const float* W1  = (const float*)d_in[2];
  const float* a1s = (const float*)d_in[3];
  const float* a1d = (const float*)d_in[4];
  const float* b1  = (const float*)d_in[5];
  const float* W2  = (const float*)d_in[6];
  const float* a2s = (const float*)d_in[7];
  const float* a2d = (const float*)d_in[8];
  const float* b2  = (const float*)d_in[9];
  float* out = (float*)d_out;

  char* ws = (char*)d_ws;
  size_t off = 0;
  auto alloc = [&](size_t bytes)->void*{ void* p = ws + off; off += (bytes + 255) & ~(size_t)255; return p; };
  unsigned short* A1hi = (unsigned short*)alloc((size_t)M_PAD*F1*2);
  unsigned short* h1bf = (unsigned short*)alloc((size_t)M_PAD*F1*2);
  unsigned short* h2bf = (unsigned short*)alloc((size_t)M_PAD*F2*2);
  unsigned short* Bt1hi= (unsigned short*)alloc((size_t)F1*DIN*2);
  unsigned short* Bt2hi= (unsigned short*)alloc((size_t)F2*F1*2);
  float* e1s   = (float*)alloc((size_t)M_PAD*HEADS*4);
  float* e1d   = (float*)alloc((size_t)M_PAD*HEADS*4);
  float* e2s   = (float*)alloc((size_t)N_NODES*4);
  float* e2d   = (float*)alloc((size_t)N_NODES*4);
  float* ex1   = (float*)alloc((size_t)EP*HEADS*4);
  float* ex2   = (float*)alloc((size_t)EP*4);
  int*   counts= (int*)alloc((size_t)N_NODES*4);
  int*   offs  = (int*)alloc((size_t)(N_NODES+1)*4);
  int*   rank  = (int*)alloc((size_t)EP*4);
  int*   exc   = (int*)alloc((size_t)N_NODES*4);
  int*   bsum  = (int*)alloc((size_t)SCAN_NBLK*4);
  int*   perm  = (int*)alloc((size_t)N_NODES*4);
  int*   dbin  = (int*)alloc((size_t)256*4);
  int*   bcount= (int*)alloc((size_t)SCAN_NBLK*256*4);
  int*   colbase=(int*)alloc((size_t)SCAN_NBLK*256*4);
  int*   ssrc  = (int*)alloc((size_t)EP*4);
  int*   sdst  = (int*)alloc((size_t)EP*4);
  unsigned short* A2hi = A1hi;   // layer-1 input dead after gemm1

  hipMemsetAsync(counts, 0, (size_t)N_NODES*4, stream);
  k_prep<<<SA_NB + WT_NB + HIST_NB, 256, 0, stream>>>(x, A1hi, W1, W2, Bt1hi, Bt2hi, edst, counts, rank);
  k_scan1<<<SCAN_NBLK, 256, 0, stream>>>(counts, exc, bsum, dbin);
  k_scan3d<<<SCAN_NBLK, 256, 0, stream>>>(exc, bsum, counts, offs, dbin, bcount);
  k_scatter_dcol_fill<<<HIST_NB + 1 + SCAN_NBLK, 256, 0, stream>>>(esrc, edst, rank, ssrc, sdst,
                                                                   dbin, bcount, colbase, offs);
  k_gemm1f<<<GEMM1_NB, 256, 0, stream>>>(A1hi, Bt1hi, a1s, a1d, h1bf, e1s, e1d);
  k_mid2<<<SCAN_NBLK + HIST_NB, 256, 0, stream>>>(counts, colbase, perm, ssrc, sdst, e1s, e1d, ex1);
  k_agg1<<<(M_PAD+3)/4, 256, 0, stream>>>(h1bf, ex1, offs, ssrc, perm, b1, A2hi);

  k_gemm2e<<<M_PAD/128, 256, 0, stream>>>(A2hi, Bt2hi, a2s, a2d, h2bf, e2s, e2d);
  k_eexp2<<<HIST_NB, 256, 0, stream>>>(ssrc, sdst, e2s, e2d, ex2);
  k_agg2<<<(N_NODES+3)/4, 256, 0, stream>>>(h2bf, ex2, offs, ssrc, perm, b2, out);
}